// Round 4
// baseline (1113.668 us; speedup 1.0000x reference)
//
#include <hip/hip_runtime.h>
#include <cstdint>

typedef __bf16 bf16;
typedef __bf16 bf16x4 __attribute__((ext_vector_type(4)));
typedef __bf16 bf16x8 __attribute__((ext_vector_type(8)));
typedef float  f32x4  __attribute__((ext_vector_type(4)));

__device__ __forceinline__ void gload_lds16(const void* gptr, void* lptr) {
  __builtin_amdgcn_global_load_lds(
      (const __attribute__((address_space(1))) unsigned int*)gptr,
      (__attribute__((address_space(3))) unsigned int*)lptr, 16, 0, 0);
}

// ---------------------------------------------------------------------------
// Small fp32 GEMM with bf16 TRANSPOSED output:
//   C = A[M,K] @ B[K,N];  CT[n*M + m] = (bf16)C[m][n]
// Used for W12T = (W1@W2)^T and kc_WhT = (kc_h@W1)^T. Tiny (<=1.3 GF total).
// ---------------------------------------------------------------------------
__global__ __launch_bounds__(256)
void gemm_small_ct(const float* __restrict__ A, const float* __restrict__ B,
                   bf16* __restrict__ CT, int M, int N, int K) {
  constexpr int BM = 64, BN = 64, BK = 16;
  __shared__ float As[BK][BM + 1];
  __shared__ float Bs[BK][BN + 1];
  const int tid = threadIdx.x;
  const int tx = tid & 15, ty = tid >> 4;
  const int m0 = blockIdx.y * BM, n0 = blockIdx.x * BN;
  float acc[4][4] = {};
  for (int k0 = 0; k0 < K; k0 += BK) {
    __syncthreads();
#pragma unroll
    for (int i = 0; i < 4; i++) {
      int idx = tid + i * 256;           // 0..1023
      int r = idx >> 4, c = idx & 15;    // A tile: 64 rows x 16 k
      As[c][r] = A[(size_t)(m0 + r) * K + (k0 + c)];
      int rb = idx >> 6, cb = idx & 63;  // B tile: 16 k x 64 cols
      Bs[rb][cb] = B[(size_t)(k0 + rb) * N + (n0 + cb)];
    }
    __syncthreads();
#pragma unroll
    for (int kk = 0; kk < BK; kk++) {
      float a[4], b[4];
#pragma unroll
      for (int i = 0; i < 4; i++) a[i] = As[kk][ty * 4 + i];
#pragma unroll
      for (int j = 0; j < 4; j++) b[j] = Bs[kk][tx * 4 + j];
#pragma unroll
      for (int i = 0; i < 4; i++)
#pragma unroll
        for (int j = 0; j < 4; j++) acc[i][j] += a[i] * b[j];
    }
  }
#pragma unroll
  for (int i = 0; i < 4; i++)
#pragma unroll
    for (int j = 0; j < 4; j++)
      CT[(size_t)(n0 + tx * 4 + j) * M + (m0 + ty * 4 + i)] = (bf16)acc[i][j];
}

// ---------------------------------------------------------------------------
// MFMA bf16 GEMM (m97 structure: 128x128 tile, BK=32, 4 waves, 2-barrier loop)
//   A: [M,K] f32 in HBM, converted f32->bf16 during reg-staging
//   BT: [N,K] bf16 (K-contiguous) staged via global_load_lds width=16
//   MODE 0: Cb[row*N+col] = (bf16)acc            (T producer)
//   MODE 1: Out[row*N+col] = elu(acc * Tm[...])  (final fused epilogue)
// ---------------------------------------------------------------------------
template <int MODE>
__global__ __launch_bounds__(256, 2)
void gemm_mfma(const float* __restrict__ A, const bf16* __restrict__ BT,
               bf16* __restrict__ Cb, const bf16* __restrict__ Tm,
               float* __restrict__ Out, int M, int N, int K) {
  constexpr int BM = 128, BN = 128, BK = 32;
  __shared__ bf16 As[BM][BK];  // 8 KB
  __shared__ bf16 Bs[BN][BK];  // 8 KB
  const int tid = threadIdx.x;
  const int wave = tid >> 6, lane = tid & 63;
  const int bn0 = blockIdx.x * BN;
  const int bm0 = blockIdx.y * BM;
  const int wr = (wave >> 1) * 64;  // wave's 64x64 quadrant
  const int wc = (wave & 1) * 64;

  f32x4 acc[4][4];
#pragma unroll
  for (int i = 0; i < 4; i++)
#pragma unroll
    for (int j = 0; j < 4; j++) acc[i][j] = (f32x4){0.f, 0.f, 0.f, 0.f};

  const int rA = lane & 15;         // fragment row within 16
  const int kh = (lane >> 4) * 8;   // fragment k-offset

  for (int k0 = 0; k0 < K; k0 += BK) {
    __syncthreads();  // previous tile's compute done before overwrite
    // B: async global->LDS, 512 x 16B chunks, LDS dest wave-uniform + lane*16
#pragma unroll
    for (int i = 0; i < 2; i++) {
      int g = i * 256 + tid;                 // 0..511
      int r = g >> 2, ks = (g & 3) * 8;      // row (n), k-sub
      const bf16* gp = BT + (size_t)(bn0 + r) * K + (k0 + ks);
      char* lp = (char*)&Bs[0][0] + (size_t)(i * 256 + wave * 64) * 16;
      gload_lds16(gp, lp);
    }
    // A: f32 load -> bf16 cvt -> LDS (1024 float4 groups)
#pragma unroll
    for (int i = 0; i < 4; i++) {
      int g = i * 256 + tid;                 // 0..1023
      int r = g >> 3, kq = (g & 7) * 4;      // row (m), k-quad
      int grow = bm0 + r;
      float4 v = make_float4(0.f, 0.f, 0.f, 0.f);
      if (grow < M) v = *(const float4*)(A + (size_t)grow * K + (k0 + kq));
      bf16x4 h;
      h[0] = (bf16)v.x; h[1] = (bf16)v.y; h[2] = (bf16)v.z; h[3] = (bf16)v.w;
      *(bf16x4*)&As[r][kq] = h;
    }
    __syncthreads();  // compiler inserts vmcnt/lgkmcnt drain here
    bf16x8 af[4], bfr[4];
#pragma unroll
    for (int m = 0; m < 4; m++) af[m] = *(const bf16x8*)&As[wr + m * 16 + rA][kh];
#pragma unroll
    for (int n = 0; n < 4; n++) bfr[n] = *(const bf16x8*)&Bs[wc + n * 16 + rA][kh];
#pragma unroll
    for (int m = 0; m < 4; m++)
#pragma unroll
      for (int n = 0; n < 4; n++)
        acc[m][n] = __builtin_amdgcn_mfma_f32_16x16x32_bf16(af[m], bfr[n],
                                                            acc[m][n], 0, 0, 0);
  }

  // epilogue: C/D layout col=lane&15, row=(lane>>4)*4+reg (m89-verified)
  const int orow = (lane >> 4) * 4;
  const int ocol = lane & 15;
#pragma unroll
  for (int m = 0; m < 4; m++) {
#pragma unroll
    for (int j = 0; j < 4; j++) {
      int row = bm0 + wr + m * 16 + orow + j;
      if (row >= M) continue;
#pragma unroll
      for (int n = 0; n < 4; n++) {
        int col = bn0 + wc + n * 16 + ocol;
        size_t idx = (size_t)row * N + col;
        float x = acc[m][n][j];
        if constexpr (MODE == 0) {
          Cb[idx] = (bf16)x;
        } else {
          float y = x * (float)Tm[idx];
          Out[idx] = y > 0.f ? y : (__expf(y) - 1.f);
        }
      }
    }
  }
}

// ---------------------------------------------------------------------------
extern "C" void kernel_launch(void* const* d_in, const int* in_sizes, int n_in,
                              void* d_out, int out_size, void* d_ws, size_t ws_size,
                              hipStream_t stream) {
  const float* ex_h = (const float*)d_in[0];  // [50000,512]
  const float* kc_h = (const float*)d_in[1];  // [2048,512]
  const float* adj  = (const float*)d_in[2];  // [50000,2048]
  const float* W1   = (const float*)d_in[3];  // [512,512]
  const float* W2   = (const float*)d_in[4];  // [512,512]
  float* out = (float*)d_out;

  const int E = 50000, KC = 2048, F = 512;

  // workspace layout (bf16): W12T [512][512], kc_WhT [512][2048], T [50000][512]
  char* ws = (char*)d_ws;
  bf16* W12T  = (bf16*)ws;                                   // 512 KB
  bf16* kcWhT = (bf16*)(ws + (size_t)F * F * 2);             // 2 MB
  bf16* T     = (bf16*)(ws + (size_t)F * F * 2 + (size_t)F * KC * 2);  // 51.2 MB

  // 1) W12T = (W1 @ W2)^T   [n][m], ld = 512
  gemm_small_ct<<<dim3(F / 64, F / 64), 256, 0, stream>>>(W1, W2, W12T, F, F, F);
  // 2) kc_WhT = (kc_h @ W1)^T  [n][k], ld = 2048
  gemm_small_ct<<<dim3(F / 64, KC / 64), 256, 0, stream>>>(kc_h, W1, kcWhT, KC, F, F);
  // 3) T = ex_h @ W12  (bf16 out)
  dim3 grid3(F / 128, (E + 127) / 128);
  gemm_mfma<0><<<grid3, 256, 0, stream>>>(ex_h, W12T, T, nullptr, nullptr, E, F, F);
  // 4) out = elu((adj @ kc_Wh) * T)
  gemm_mfma<1><<<grid3, 256, 0, stream>>>(adj, kcWhT, nullptr, T, out, E, F, KC);
}

// Round 6
// 873.584 us; speedup vs baseline: 1.2748x; 1.2748x over previous
//
#include <hip/hip_runtime.h>
#include <cstdint>

typedef __bf16 bf16;
typedef __bf16 bf16x4 __attribute__((ext_vector_type(4)));
typedef __bf16 bf16x8 __attribute__((ext_vector_type(8)));
typedef float  f32x4  __attribute__((ext_vector_type(4)));

__device__ __forceinline__ void gload_lds16(const void* gptr, void* lptr) {
  __builtin_amdgcn_global_load_lds(
      (const __attribute__((address_space(1))) unsigned int*)gptr,
      (__attribute__((address_space(3))) unsigned int*)lptr, 16, 0, 0);
}

// ---------------------------------------------------------------------------
// Small fp32 GEMM with bf16 TRANSPOSED output (unchanged, tiny):
//   C = A[M,K] @ B[K,N];  CT[n*M + m] = (bf16)C[m][n]
// ---------------------------------------------------------------------------
__global__ __launch_bounds__(256)
void gemm_small_ct(const float* __restrict__ A, const float* __restrict__ B,
                   bf16* __restrict__ CT, int M, int N, int K) {
  constexpr int BK = 16;
  __shared__ float As[BK][64 + 1];
  __shared__ float Bs[BK][64 + 1];
  const int tid = threadIdx.x;
  const int tx = tid & 15, ty = tid >> 4;
  const int m0 = blockIdx.y * 64, n0 = blockIdx.x * 64;
  float acc[4][4] = {};
  for (int k0 = 0; k0 < K; k0 += BK) {
    __syncthreads();
#pragma unroll
    for (int i = 0; i < 4; i++) {
      int idx = tid + i * 256;
      int r = idx >> 4, c = idx & 15;
      As[c][r] = A[(size_t)(m0 + r) * K + (k0 + c)];
      int rb = idx >> 6, cb = idx & 63;
      Bs[rb][cb] = B[(size_t)(k0 + rb) * N + (n0 + cb)];
    }
    __syncthreads();
#pragma unroll
    for (int kk = 0; kk < BK; kk++) {
      float a[4], b[4];
#pragma unroll
      for (int i = 0; i < 4; i++) a[i] = As[kk][ty * 4 + i];
#pragma unroll
      for (int j = 0; j < 4; j++) b[j] = Bs[kk][tx * 4 + j];
#pragma unroll
      for (int i = 0; i < 4; i++)
#pragma unroll
        for (int j = 0; j < 4; j++) acc[i][j] += a[i] * b[j];
    }
  }
#pragma unroll
  for (int i = 0; i < 4; i++)
#pragma unroll
    for (int j = 0; j < 4; j++)
      CT[(size_t)(n0 + tx * 4 + j) * M + (m0 + ty * 4 + i)] = (bf16)acc[i][j];
}

// ---------------------------------------------------------------------------
// MFMA GEMM, fully-async staging:
//   A: [M,K] f32 staged RAW via global_load_lds (48KB LDS: A-f32 32KB + B 16KB),
//      converted f32->bf16 at frag-read. Tail rows CLAMPED (outputs discarded).
//   BT: [N,K] bf16 staged via global_load_lds.
//   Both tiles use T2 chunk-XOR swizzle: LDS dest stays LINEAR (m104 rule);
//   the GLOBAL source k-chunk is pre-swizzled (c ^= row&7), and frag reads
//   apply the same XOR (involution, rule #21).
//   BK=64 (2 MFMA k-chunks per stage), 4 waves, 128x128 tile.
//   MODE 0: Cb = (bf16)acc        MODE 1: Out = elu(acc * Tm)
// ---------------------------------------------------------------------------
template <int MODE>
__global__ __launch_bounds__(256, 2)
void gemm_mfma2(const float* __restrict__ A, const bf16* __restrict__ BT,
                bf16* __restrict__ Cb, const bf16* __restrict__ Tm,
                float* __restrict__ Out, int M, int N, int K) {
  constexpr int BM = 128, BN = 128, BK = 64;
  __shared__ float As[BM][BK];  // 32 KB (f32, swizzled 16B chunks)
  __shared__ bf16  Bs[BN][BK];  // 16 KB (bf16, swizzled 16B chunks)
  float* Asf = &As[0][0];
  bf16*  Bsf = &Bs[0][0];

  const int tid = threadIdx.x;
  const int wave = tid >> 6, lane = tid & 63;

  // --- bijective XCD swizzle (m204): consecutive wg on same XCD share adj panel
  int id = blockIdx.y * gridDim.x + blockIdx.x;       // HW dispatch order, x fastest
  int nwg = gridDim.x * gridDim.y;
  int q = nwg >> 3, rr = nwg & 7;
  int xcd = id & 7, j = id >> 3;
  int wg = (xcd < rr) ? xcd * (q + 1) + j : rr * (q + 1) + (xcd - rr) * q + j;
  const int bn0 = (wg & 3) * BN;   // gridDim.x == 4 (N=512) for all callers
  const int bm0 = (wg >> 2) * BM;

  const int wr = (wave >> 1) * 64;  // wave's 64x64 quadrant of the 128x128 tile
  const int wc = (wave & 1) * 64;

  f32x4 acc[4][4];
#pragma unroll
  for (int i = 0; i < 4; i++)
#pragma unroll
    for (int j2 = 0; j2 < 4; j2++) acc[i][j2] = (f32x4){0.f, 0.f, 0.f, 0.f};

  const int rA = lane & 15;        // fragment row within 16
  const int qh = lane >> 4;        // k-quarter 0..3

  for (int k0 = 0; k0 < K; k0 += BK) {
    __syncthreads();  // previous iteration's frag reads done before overwrite

    // B: 1024 16B chunks (8 per row), 4 per thread. LDS dest linear (g*16);
    // global k-chunk pre-swizzled by row&7.
#pragma unroll
    for (int i = 0; i < 4; i++) {
      int g = i * 256 + tid;                       // 0..1023
      int r = g >> 3, c = g & 7;
      int kc = c ^ (r & 7);                        // pre-swizzled source chunk
      const bf16* gp = BT + (size_t)(bn0 + r) * K + (k0 + kc * 8);
      gload_lds16(gp, (char*)Bsf + (size_t)g * 16);
    }
    // A (f32, raw): 2048 16B chunks (16 per row = 64 f32), 8 per thread.
#pragma unroll
    for (int i = 0; i < 8; i++) {
      int g = i * 256 + tid;                       // 0..2047
      int r = g >> 4, c = g & 15;
      int kc = c ^ (r & 7);                        // XOR low-3 bits only
      int grow = bm0 + r; if (grow > M - 1) grow = M - 1;  // clamp tail (no fault)
      const float* gp = A + (size_t)grow * K + (k0 + kc * 4);
      gload_lds16(gp, (char*)Asf + (size_t)g * 16);
    }
    __syncthreads();  // compiler drains vmcnt(0) here — loads overlap each other

#pragma unroll
    for (int kk = 0; kk < 2; kk++) {
      // A frags: 8 f32 at k = kk*32 + qh*8 -> two swizzled 16B chunks -> cvt bf16
      bf16x8 af[4];
#pragma unroll
      for (int m = 0; m < 4; m++) {
        int row = wr + m * 16 + rA;
        int c0 = kk * 8 + qh * 2;
        f32x4 lo = *(const f32x4*)(Asf + (size_t)row * 64 + ((c0 ^ (row & 7))) * 4);
        f32x4 hi = *(const f32x4*)(Asf + (size_t)row * 64 + (((c0 + 1) ^ (row & 7))) * 4);
        bf16x8 h;
        h[0] = (bf16)lo[0]; h[1] = (bf16)lo[1]; h[2] = (bf16)lo[2]; h[3] = (bf16)lo[3];
        h[4] = (bf16)hi[0]; h[5] = (bf16)hi[1]; h[6] = (bf16)hi[2]; h[7] = (bf16)hi[3];
        af[m] = h;
      }
      bf16x8 bfr[4];
#pragma unroll
      for (int n = 0; n < 4; n++) {
        int row = wc + n * 16 + rA;
        int c0 = kk * 4 + qh;                      // one 16B chunk = 8 bf16
        bfr[n] = *(const bf16x8*)(Bsf + (size_t)row * 64 + ((c0 ^ (row & 7))) * 8);
      }
#pragma unroll
      for (int m = 0; m < 4; m++)
#pragma unroll
        for (int n = 0; n < 4; n++)
          acc[m][n] = __builtin_amdgcn_mfma_f32_16x16x32_bf16(af[m], bfr[n],
                                                              acc[m][n], 0, 0, 0);
    }
  }

  // epilogue: C/D layout col=lane&15, row=(lane>>4)*4+reg (m89-verified)
  const int orow = qh * 4;
  const int ocol = rA;
#pragma unroll
  for (int m = 0; m < 4; m++) {
#pragma unroll
    for (int j2 = 0; j2 < 4; j2++) {
      int row = bm0 + wr + m * 16 + orow + j2;
      if (row >= M) continue;
#pragma unroll
      for (int n = 0; n < 4; n++) {
        int col = bn0 + wc + n * 16 + ocol;
        size_t idx = (size_t)row * N + col;
        float x = acc[m][n][j2];
        if constexpr (MODE == 0) {
          Cb[idx] = (bf16)x;
        } else {
          float y = x * (float)Tm[idx];
          Out[idx] = y > 0.f ? y : (__expf(y) - 1.f);
        }
      }
    }
  }
}

// ---------------------------------------------------------------------------
extern "C" void kernel_launch(void* const* d_in, const int* in_sizes, int n_in,
                              void* d_out, int out_size, void* d_ws, size_t ws_size,
                              hipStream_t stream) {
  const float* ex_h = (const float*)d_in[0];  // [50000,512]
  const float* kc_h = (const float*)d_in[1];  // [2048,512]
  const float* adj  = (const float*)d_in[2];  // [50000,2048]
  const float* W1   = (const float*)d_in[3];  // [512,512]
  const float* W2   = (const float*)d_in[4];  // [512,512]
  float* out = (float*)d_out;

  const int E = 50000, KC = 2048, F = 512;

  // workspace (bf16): W12T [512][512], kc_WhT [512][2048], T [50000][512] = 53.9MB
  char* ws = (char*)d_ws;
  bf16* W12T  = (bf16*)ws;                                             // 512 KB
  bf16* kcWhT = (bf16*)(ws + (size_t)F * F * 2);                       // 2 MB
  bf16* T     = (bf16*)(ws + (size_t)F * F * 2 + (size_t)F * KC * 2);  // 51.2 MB

  // 1) W12T = (W1 @ W2)^T   [n][m], ld = 512
  gemm_small_ct<<<dim3(F / 64, F / 64), 256, 0, stream>>>(W1, W2, W12T, F, F, F);
  // 2) kc_WhT = (kc_h @ W1)^T  [n][k], ld = 2048
  gemm_small_ct<<<dim3(F / 64, KC / 64), 256, 0, stream>>>(kc_h, W1, kcWhT, KC, F, F);
  // 3) T = ex_h @ W12  (bf16 out), A = f32 direct
  dim3 grid3(F / 128, (E + 127) / 128);
  gemm_mfma2<0><<<grid3, 256, 0, stream>>>(ex_h, W12T, T, nullptr, nullptr, E, F, F);
  // 4) out = elu((adj @ kc_Wh) * T), A = f32 direct
  gemm_mfma2<1><<<grid3, 256, 0, stream>>>(adj, kcWhT, nullptr, T, out, E, F, KC);
}